// Round 7
// baseline (253.452 us; speedup 1.0000x reference)
//
#include <hip/hip_runtime.h>

// rosa_4bit_layer: causal linear attention with per-head 4x4 state.
//   S_t = S_{t-1} + k_t v_t^T ;  o_t = q_t^T S_t ;  out = o * emb
// Shapes: x{q,k,v}: (B=4, T=4096, C=512) fp32, emb: (1,1,512) fp32.
// H = 128 heads, head_dim = 4 (contiguous 4-float groups in C).
//
// R6 post-mortem: k_out at 54.5 us with WRITE_SIZE = 2x output size.
// The 8 hg-blocks of one (b,c) wrote interleaved 256B slices of each 2KB
// output row from DIFFERENT XCDs -> memory-side sectors written twice.
// Also k,v went through VMEM twice (aggregate pass + replay).
//
// R7 fixes, keeping R6's verified scan structure:
//  1. XCD-grouping swizzle: blockIdx = bcl + 128*hg, so all 8 hg-blocks of
//     a given (b,c) share idx%8 -> same XCD under round-robin dispatch ->
//     each output row is dirtied in ONE L2 -> full-sector writes.
//  2. olocal-in-registers: phase A computes o_local,t = q_t.S_local while
//     aggregating (k,v read once); after the LDS scan the correction loop
//     only reloads q (L1-hot) and writes out.
// Thread (h,e) owns column e of head h's 4x4 state: S[d][e], d=0..3.

constexpr int B   = 4;
constexpr int T   = 4096;
constexpr int C   = 512;
constexpr int HG  = 8;          // head groups (16 heads = 64 floats each)
constexpr int NC  = 32;         // chunks per sequence
constexpr int CT  = T / NC;     // 128 timesteps per chunk
constexpr int SUB = 8;          // sub-chunks per block (= waves)
constexpr int TS  = CT / SUB;   // 16 timesteps per thread
constexpr int NBLK = B * HG * NC;  // 1024
// agg: one float4 per (logical block, lane): NBLK*64*16B = 1 MiB in d_ws.

__device__ __forceinline__ void fma4(float4& a, const float4& k4, float ve) {
  a.x += k4.x * ve; a.y += k4.y * ve; a.z += k4.z * ve; a.w += k4.w * ve;
}
__device__ __forceinline__ void add4(float4& a, const float4& b) {
  a.x += b.x; a.y += b.y; a.z += b.z; a.w += b.w;
}
__device__ __forceinline__ float dot4(const float4& a, const float4& b) {
  return a.x * b.x + a.y * b.y + a.z * b.z + a.w * b.w;
}

__global__ __launch_bounds__(512, 8) void k_partial(const float* __restrict__ k,
                                                    const float* __restrict__ v,
                                                    float4* __restrict__ agg) {
  const int bc   = blockIdx.x;          // logical ((b*HG+hg)*NC + c)
  const int b    = bc >> 8;
  const int hg   = (bc >> 5) & 7;
  const int c    = bc & 31;
  const int tid  = threadIdx.x;
  const int sg   = tid >> 6;            // sub-chunk == wave index (uniform)
  const int lane = tid & 63;
  const int h    = lane >> 2;
  const int e    = lane & 3;

  const int t0 = c * CT + sg * TS;
  const size_t base = ((size_t)b * T + t0) * (size_t)C + hg * 64 + (h << 2);
  const float* kb = k + base;
  const float* vb = v + base + e;

  float4 A = {0.f, 0.f, 0.f, 0.f};
#pragma unroll
  for (int t = 0; t < TS; ++t) {
    const float4 k4 = *reinterpret_cast<const float4*>(kb + (size_t)t * C);
    fma4(A, k4, vb[(size_t)t * C]);
  }

  __shared__ float4 lds[SUB][64];
  lds[sg][lane] = A;
  __syncthreads();
  if (sg == 0) {
    float4 s = lds[0][lane];
#pragma unroll
    for (int g = 1; g < SUB; ++g) add4(s, lds[g][lane]);
    agg[(size_t)bc * 64 + lane] = s;    // 1 KiB per block, wave-coalesced
  }
}

__global__ __launch_bounds__(512, 8) void k_out(const float* __restrict__ q,
                                                const float* __restrict__ k,
                                                const float* __restrict__ v,
                                                const float* __restrict__ emb,
                                                const float4* __restrict__ agg,
                                                float* __restrict__ out) {
  // XCD-grouping swizzle: idx = bcl + 128*hg  ->  idx%8 == bcl%8 for all hg
  // -> the 8 hg-blocks of one (b,c) land on the same XCD (round-robin model).
  const int bcl  = blockIdx.x & 127;    // (b,c) tile
  const int hg   = blockIdx.x >> 7;
  const int b    = bcl >> 5;
  const int c    = bcl & 31;
  const int lbc  = ((b * HG + hg) << 5) + c;   // logical block for agg
  const int tid  = threadIdx.x;
  const int sg   = tid >> 6;            // wave-uniform
  const int lane = tid & 63;
  const int h    = lane >> 2;
  const int e    = lane & 3;

  // ---- gather predecessor chunk aggregates, split across the 8 waves ----
  const size_t col = ((size_t)lbc - c) * 64 + lane;  // column base (cc = 0)
  float4 G = {0.f, 0.f, 0.f, 0.f};
#pragma unroll
  for (int i = 0; i < 4; ++i) {
    const int cc = sg + i * 8;
    if (cc < c) {
      const float4 a = agg[col + (size_t)cc * 64];
      add4(G, a);
    }
  }

  // ---- phase A: local aggregate + o_local in registers (k,v read ONCE) ----
  const int t0 = c * CT + sg * TS;
  const size_t base = ((size_t)b * T + t0) * (size_t)C + hg * 64 + (h << 2);
  const float* kb = k + base;
  const float* vb = v + base + e;
  const float* qb = q + base;

  float olocal[TS];
  float4 A = {0.f, 0.f, 0.f, 0.f};
#pragma unroll
  for (int t = 0; t < TS; ++t) {
    const float4 k4 = *reinterpret_cast<const float4*>(kb + (size_t)t * C);
    const float4 q4 = *reinterpret_cast<const float4*>(qb + (size_t)t * C);
    fma4(A, k4, vb[(size_t)t * C]);
    olocal[t] = dot4(q4, A);
  }

  // ---- combine: block-start prefix + exclusive in-block sub-chunk scan ----
  __shared__ float4 lds_g[SUB][64];
  __shared__ float4 lds_s[SUB][64];
  lds_g[sg][lane] = G;
  lds_s[sg][lane] = A;
  __syncthreads();

  float4 P = {0.f, 0.f, 0.f, 0.f};
#pragma unroll
  for (int g = 0; g < SUB; ++g) add4(P, lds_g[g][lane]);   // global prefix
#pragma unroll
  for (int g = 0; g < SUB - 1; ++g)
    if (g < sg) add4(P, lds_s[g][lane]);                   // uniform: no div

  // ---- correction: o_t = olocal[t] + q_t.P ; q reload is L1-hot ----
  float* ob = out + base + e;
  const float embv = emb[hg * 64 + (h << 2) + e];
#pragma unroll
  for (int t = 0; t < TS; ++t) {
    const float4 q4 = *reinterpret_cast<const float4*>(qb + (size_t)t * C);
    ob[(size_t)t * C] = (olocal[t] + dot4(q4, P)) * embv;
  }
}

extern "C" void kernel_launch(void* const* d_in, const int* in_sizes, int n_in,
                              void* d_out, int out_size, void* d_ws, size_t ws_size,
                              hipStream_t stream) {
  const float* xq  = (const float*)d_in[0];
  const float* xk  = (const float*)d_in[1];
  const float* xv  = (const float*)d_in[2];
  const float* emb = (const float*)d_in[3];
  float*  out = (float*)d_out;
  float4* agg = (float4*)d_ws;   // 1 MiB

  k_partial<<<NBLK, 512, 0, stream>>>(xk, xv, agg);
  k_out<<<NBLK, 512, 0, stream>>>(xq, xk, xv, emb, agg, out);
}

// Round 8
// 175.565 us; speedup vs baseline: 1.4436x; 1.4436x over previous
//
#include <hip/hip_runtime.h>

// rosa_4bit_layer: causal linear attention with per-head 4x4 state.
//   S_t = S_{t-1} + k_t v_t^T ;  o_t = q_t^T S_t ;  out = o * emb
// Shapes: x{q,k,v}: (B=4, T=4096, C=512) fp32, emb: (1,1,512) fp32.
// H = 128 heads, head_dim = 4 (contiguous 4-float groups in C).
//
// R7 post-mortem: launch_bounds(512,8)'s 64-VGPR cap spilled olocal+q
// state to scratch -> WRITE 8x output, 137 us. R6/R3 lesson: all
// channel-column-per-thread kernels plateau at ~3.1-3.3 TB/s fabric
// (256B-per-wave strided slices, 4-way duplicated loads), while the
// harness fill streams 6.5 TB/s at 8% occupancy -> LINEARITY is the
// limiter, not occupancy.
//
// R8: thread = (head h, t-subrange) owning the FULL 4x4 state in 16 VGPRs.
// Block = (b, chunk c of CT=32) x 512 threads = 4 subchunks x 128 heads.
// Every k4/v4/q4 load and o4 store: 64 consecutive-head lanes x 16 B =
// 1 KB contiguous per wave, no duplication, float4 stores.
// 3 dispatches (proven structure): partial -> parallel scan -> out.
// launch_bounds(512,4): 128-VGPR budget, NO spill (R7 lesson).

constexpr int B   = 4;
constexpr int T   = 4096;
constexpr int C   = 512;
constexpr int H   = 128;        // heads
constexpr int NC  = 128;        // chunks per sequence
constexpr int CT  = T / NC;     // 32 timesteps per chunk
constexpr int SG  = 4;          // t-subchunks per block
constexpr int TSS = CT / SG;    // 8 timesteps per thread
constexpr int NBLK = B * NC;    // 512 blocks
// part: B*NC rows of 2048 floats (h*16 + d*4 + e) = 4 MiB in d_ws.

__device__ __forceinline__ void fmadd4(float4& a, float s, const float4& b) {
  a.x += s * b.x; a.y += s * b.y; a.z += s * b.z; a.w += s * b.w;
}
__device__ __forceinline__ void add4(float4& a, const float4& b) {
  a.x += b.x; a.y += b.y; a.z += b.z; a.w += b.w;
}

__global__ __launch_bounds__(512, 4) void k_partial(const float* __restrict__ k,
                                                    const float* __restrict__ v,
                                                    float4* __restrict__ part) {
  const int bc  = blockIdx.x;          // b*NC + c
  const int b   = bc >> 7;
  const int c   = bc & (NC - 1);
  const int tid = threadIdx.x;
  const int sg  = tid >> 7;            // t-subchunk 0..3 (wave-uniform)
  const int h   = tid & 127;           // head (consecutive within wave)
  const int t0  = c * CT + sg * TSS;

  const size_t rb = ((size_t)b * T + t0) * (size_t)C + h * 4;
  const float* kp = k + rb;
  const float* vp = v + rb;

  float4 S0{0,0,0,0}, S1{0,0,0,0}, S2{0,0,0,0}, S3{0,0,0,0};
#pragma unroll
  for (int t = 0; t < TSS; ++t) {
    const float4 k4 = *reinterpret_cast<const float4*>(kp + (size_t)t * C);
    const float4 v4 = *reinterpret_cast<const float4*>(vp + (size_t)t * C);
    fmadd4(S0, k4.x, v4); fmadd4(S1, k4.y, v4);
    fmadd4(S2, k4.z, v4); fmadd4(S3, k4.w, v4);
  }

  __shared__ float4 lds[SG][4][H];     // 32 KiB; lanes->consec 16B: clean
  lds[sg][0][h] = S0; lds[sg][1][h] = S1;
  lds[sg][2][h] = S2; lds[sg][3][h] = S3;
  __syncthreads();
  if (sg == 0) {
#pragma unroll
    for (int g = 1; g < SG; ++g) {
      add4(S0, lds[g][0][h]); add4(S1, lds[g][1][h]);
      add4(S2, lds[g][2][h]); add4(S3, lds[g][3][h]);
    }
    float4* pr = part + (size_t)bc * 512 + h * 4;
    pr[0] = S0; pr[1] = S1; pr[2] = S2; pr[3] = S3;
  }
}

// Parallel exclusive scan over the NC=128 chunks of each sequence.
// 128 blocks (b x 32 j-tiles) x 512 threads (8 c-groups x 64 j lanes).
__global__ __launch_bounds__(512, 4) void k_scan(float* __restrict__ part) {
  const int sb  = blockIdx.x >> 5;
  const int jt  = blockIdx.x & 31;
  const int tid = threadIdx.x;
  const int jl  = tid & 63;
  const int cg  = tid >> 6;            // wave-uniform
  const int j   = jt * 64 + jl;
  float* bp = part + (size_t)sb * NC * 2048 + j;
  const int c0 = cg * 16;
  float vals[16];
#pragma unroll
  for (int i = 0; i < 16; ++i) vals[i] = bp[(size_t)(c0 + i) * 2048];
  float sum = 0.f;
#pragma unroll
  for (int i = 0; i < 16; ++i) sum += vals[i];
  __shared__ float ls[8][64];
  ls[cg][jl] = sum;
  __syncthreads();
  float run = 0.f;
#pragma unroll
  for (int g = 0; g < 7; ++g)
    if (g < cg) run += ls[g][jl];
#pragma unroll
  for (int i = 0; i < 16; ++i) {
    bp[(size_t)(c0 + i) * 2048] = run;   // exclusive prefix
    run += vals[i];
  }
}

__global__ __launch_bounds__(512, 4) void k_out(const float* __restrict__ q,
                                                const float* __restrict__ k,
                                                const float* __restrict__ v,
                                                const float* __restrict__ emb,
                                                const float4* __restrict__ part,
                                                float* __restrict__ out) {
  const int bc  = blockIdx.x;
  const int b   = bc >> 7;
  const int c   = bc & (NC - 1);
  const int tid = threadIdx.x;
  const int sg  = tid >> 7;            // wave-uniform
  const int h   = tid & 127;
  const int t0  = c * CT + sg * TSS;

  // chunk-start prefix: issue early so latency hides under phase A
  const float4* pr = part + (size_t)bc * 512 + h * 4;
  float4 P0 = pr[0], P1 = pr[1], P2 = pr[2], P3 = pr[3];

  const size_t rb = ((size_t)b * T + t0) * (size_t)C + h * 4;
  const float* kp = k + rb;
  const float* vp = v + rb;
  const float* qp = q + rb;

  // ---- phase A: local aggregate + o_local (k,v,q read once, 1KB/wave) ----
  float4 olocal[TSS];                  // statically indexed, 128-VGPR budget
  float4 A0{0,0,0,0}, A1{0,0,0,0}, A2{0,0,0,0}, A3{0,0,0,0};
#pragma unroll
  for (int t = 0; t < TSS; ++t) {
    const float4 k4 = *reinterpret_cast<const float4*>(kp + (size_t)t * C);
    const float4 v4 = *reinterpret_cast<const float4*>(vp + (size_t)t * C);
    const float4 q4 = *reinterpret_cast<const float4*>(qp + (size_t)t * C);
    fmadd4(A0, k4.x, v4); fmadd4(A1, k4.y, v4);
    fmadd4(A2, k4.z, v4); fmadd4(A3, k4.w, v4);
    float4 o{0.f, 0.f, 0.f, 0.f};
    fmadd4(o, q4.x, A0); fmadd4(o, q4.y, A1);
    fmadd4(o, q4.z, A2); fmadd4(o, q4.w, A3);
    olocal[t] = o;
  }

  // ---- exchange sub-chunk aggregates; thread-start state S ----
  __shared__ float4 lds[SG][4][H];     // 32 KiB
  lds[sg][0][h] = A0; lds[sg][1][h] = A1;
  lds[sg][2][h] = A2; lds[sg][3][h] = A3;
  __syncthreads();
  float4 S0 = P0, S1 = P1, S2 = P2, S3 = P3;
#pragma unroll
  for (int g = 0; g < SG - 1; ++g) {
    if (g < sg) {                      // sg wave-uniform: no divergence
      add4(S0, lds[g][0][h]); add4(S1, lds[g][1][h]);
      add4(S2, lds[g][2][h]); add4(S3, lds[g][3][h]);
    }
  }

  // ---- correction: o_t = olocal[t] + q_t^T S_start ; q reload L1/L2-hot ----
  const float4 e4 = *reinterpret_cast<const float4*>(emb + h * 4);
  float* op = out + rb;
#pragma unroll
  for (int t = 0; t < TSS; ++t) {
    const float4 q4 = *reinterpret_cast<const float4*>(qp + (size_t)t * C);
    float4 o = olocal[t];
    fmadd4(o, q4.x, S0); fmadd4(o, q4.y, S1);
    fmadd4(o, q4.z, S2); fmadd4(o, q4.w, S3);
    o.x *= e4.x; o.y *= e4.y; o.z *= e4.z; o.w *= e4.w;
    *reinterpret_cast<float4*>(op + (size_t)t * C) = o;
  }
}

extern "C" void kernel_launch(void* const* d_in, const int* in_sizes, int n_in,
                              void* d_out, int out_size, void* d_ws, size_t ws_size,
                              hipStream_t stream) {
  const float* xq  = (const float*)d_in[0];
  const float* xk  = (const float*)d_in[1];
  const float* xv  = (const float*)d_in[2];
  const float* emb = (const float*)d_in[3];
  float*  out  = (float*)d_out;
  float4* part = (float4*)d_ws;   // 4 MiB

  k_partial<<<NBLK, 512, 0, stream>>>(xk, xv, part);
  k_scan<<<B * 32, 512, 0, stream>>>((float*)d_ws);
  k_out<<<NBLK, 512, 0, stream>>>(xq, xk, xv, emb, part, out);
}

// Round 9
// 148.004 us; speedup vs baseline: 1.7125x; 1.1862x over previous
//
#include <hip/hip_runtime.h>

// rosa_4bit_layer: causal linear attention with per-head 4x4 state.
//   S_t = S_{t-1} + k_t v_t^T ;  o_t = q_t^T S_t ;  out = o * emb
// Shapes: x{q,k,v}: (B=4, T=4096, C=512) fp32, emb: (1,1,512) fp32.
// H = 128 heads, head_dim = 4 (contiguous 4-float groups in C).
//
// R8 post-mortem: k_out spilled AGAIN (VGPR_Count=64, WRITE 3.2x output,
// dispatch-0 scratch stall). Across R6/R7/R8 the VGPR caps fit hipcc
// treating launch_bounds' 2nd arg CUDA-style as BLOCKS/CU:
//   cap ~= 2048 / (blocks * 8 waves): (512,8)->32, (512,4)->64 VGPR.
// The head-linear layout itself is vindicated: 3.8 TB/s even while
// round-tripping ~70 MB of scratch.
//
// R9: k_out gets __launch_bounds__(512, 2) -> 128-VGPR cap (2 blocks/CU)
// under the observed semantics, 256 under the documented one. Kernel needs
// ~100 VGPR -> no spill either way. Everything else identical to R8:
// thread = (head h, t-subrange) owning the full 4x4 state in 16 VGPRs;
// every k4/v4/q4 load and o4 store is 1 KB contiguous per wave;
// 3 dispatches: partial -> parallel scan -> out.

constexpr int B   = 4;
constexpr int T   = 4096;
constexpr int C   = 512;
constexpr int H   = 128;        // heads
constexpr int NC  = 128;        // chunks per sequence
constexpr int CT  = T / NC;     // 32 timesteps per chunk
constexpr int SG  = 4;          // t-subchunks per block
constexpr int TSS = CT / SG;    // 8 timesteps per thread
constexpr int NBLK = B * NC;    // 512 blocks
// part: B*NC rows of 2048 floats (h*16 + d*4 + e) = 4 MiB in d_ws.

__device__ __forceinline__ void fmadd4(float4& a, float s, const float4& b) {
  a.x += s * b.x; a.y += s * b.y; a.z += s * b.z; a.w += s * b.w;
}
__device__ __forceinline__ void add4(float4& a, const float4& b) {
  a.x += b.x; a.y += b.y; a.z += b.z; a.w += b.w;
}

__global__ __launch_bounds__(512, 4) void k_partial(const float* __restrict__ k,
                                                    const float* __restrict__ v,
                                                    float4* __restrict__ part) {
  const int bc  = blockIdx.x;          // b*NC + c
  const int b   = bc >> 7;
  const int c   = bc & (NC - 1);
  const int tid = threadIdx.x;
  const int sg  = tid >> 7;            // t-subchunk 0..3 (wave-uniform)
  const int h   = tid & 127;           // head (consecutive within wave)
  const int t0  = c * CT + sg * TSS;

  const size_t rb = ((size_t)b * T + t0) * (size_t)C + h * 4;
  const float* kp = k + rb;
  const float* vp = v + rb;

  float4 S0{0,0,0,0}, S1{0,0,0,0}, S2{0,0,0,0}, S3{0,0,0,0};
#pragma unroll
  for (int t = 0; t < TSS; ++t) {
    const float4 k4 = *reinterpret_cast<const float4*>(kp + (size_t)t * C);
    const float4 v4 = *reinterpret_cast<const float4*>(vp + (size_t)t * C);
    fmadd4(S0, k4.x, v4); fmadd4(S1, k4.y, v4);
    fmadd4(S2, k4.z, v4); fmadd4(S3, k4.w, v4);
  }

  __shared__ float4 lds[SG][4][H];     // 32 KiB; lanes->consec 16B: clean
  lds[sg][0][h] = S0; lds[sg][1][h] = S1;
  lds[sg][2][h] = S2; lds[sg][3][h] = S3;
  __syncthreads();
  if (sg == 0) {
#pragma unroll
    for (int g = 1; g < SG; ++g) {
      add4(S0, lds[g][0][h]); add4(S1, lds[g][1][h]);
      add4(S2, lds[g][2][h]); add4(S3, lds[g][3][h]);
    }
    float4* pr = part + (size_t)bc * 512 + h * 4;
    pr[0] = S0; pr[1] = S1; pr[2] = S2; pr[3] = S3;
  }
}

// Parallel exclusive scan over the NC=128 chunks of each sequence.
// 128 blocks (b x 32 j-tiles) x 512 threads (8 c-groups x 64 j lanes).
__global__ __launch_bounds__(512, 4) void k_scan(float* __restrict__ part) {
  const int sb  = blockIdx.x >> 5;
  const int jt  = blockIdx.x & 31;
  const int tid = threadIdx.x;
  const int jl  = tid & 63;
  const int cg  = tid >> 6;            // wave-uniform
  const int j   = jt * 64 + jl;
  float* bp = part + (size_t)sb * NC * 2048 + j;
  const int c0 = cg * 16;
  float vals[16];
#pragma unroll
  for (int i = 0; i < 16; ++i) vals[i] = bp[(size_t)(c0 + i) * 2048];
  float sum = 0.f;
#pragma unroll
  for (int i = 0; i < 16; ++i) sum += vals[i];
  __shared__ float ls[8][64];
  ls[cg][jl] = sum;
  __syncthreads();
  float run = 0.f;
#pragma unroll
  for (int g = 0; g < 7; ++g)
    if (g < cg) run += ls[g][jl];
#pragma unroll
  for (int i = 0; i < 16; ++i) {
    bp[(size_t)(c0 + i) * 2048] = run;   // exclusive prefix
    run += vals[i];
  }
}

__global__ __launch_bounds__(512, 2) void k_out(const float* __restrict__ q,
                                                const float* __restrict__ k,
                                                const float* __restrict__ v,
                                                const float* __restrict__ emb,
                                                const float4* __restrict__ part,
                                                float* __restrict__ out) {
  const int bc  = blockIdx.x;
  const int b   = bc >> 7;
  const int c   = bc & (NC - 1);
  const int tid = threadIdx.x;
  const int sg  = tid >> 7;            // wave-uniform
  const int h   = tid & 127;
  const int t0  = c * CT + sg * TSS;

  // chunk-start prefix: issue early so latency hides under phase A
  const float4* pr = part + (size_t)bc * 512 + h * 4;
  float4 P0 = pr[0], P1 = pr[1], P2 = pr[2], P3 = pr[3];

  const size_t rb = ((size_t)b * T + t0) * (size_t)C + h * 4;
  const float* kp = k + rb;
  const float* vp = v + rb;
  const float* qp = q + rb;

  // ---- phase A: local aggregate + o_local (k,v,q read once, 1KB/wave) ----
  float4 olocal[TSS];                  // statically indexed; needs ~100 VGPR
  float4 A0{0,0,0,0}, A1{0,0,0,0}, A2{0,0,0,0}, A3{0,0,0,0};
#pragma unroll
  for (int t = 0; t < TSS; ++t) {
    const float4 k4 = *reinterpret_cast<const float4*>(kp + (size_t)t * C);
    const float4 v4 = *reinterpret_cast<const float4*>(vp + (size_t)t * C);
    const float4 q4 = *reinterpret_cast<const float4*>(qp + (size_t)t * C);
    fmadd4(A0, k4.x, v4); fmadd4(A1, k4.y, v4);
    fmadd4(A2, k4.z, v4); fmadd4(A3, k4.w, v4);
    float4 o{0.f, 0.f, 0.f, 0.f};
    fmadd4(o, q4.x, A0); fmadd4(o, q4.y, A1);
    fmadd4(o, q4.z, A2); fmadd4(o, q4.w, A3);
    olocal[t] = o;
  }

  // ---- exchange sub-chunk aggregates; thread-start state S ----
  __shared__ float4 lds[SG][4][H];     // 32 KiB; 2 blocks/CU = 64 KiB: ok
  lds[sg][0][h] = A0; lds[sg][1][h] = A1;
  lds[sg][2][h] = A2; lds[sg][3][h] = A3;
  __syncthreads();
  float4 S0 = P0, S1 = P1, S2 = P2, S3 = P3;
#pragma unroll
  for (int g = 0; g < SG - 1; ++g) {
    if (g < sg) {                      // sg wave-uniform: no divergence
      add4(S0, lds[g][0][h]); add4(S1, lds[g][1][h]);
      add4(S2, lds[g][2][h]); add4(S3, lds[g][3][h]);
    }
  }

  // ---- correction: o_t = olocal[t] + q_t^T S_start ; q reload L1/L2-hot ----
  const float4 e4 = *reinterpret_cast<const float4*>(emb + h * 4);
  float* op = out + rb;
#pragma unroll
  for (int t = 0; t < TSS; ++t) {
    const float4 q4 = *reinterpret_cast<const float4*>(qp + (size_t)t * C);
    float4 o = olocal[t];
    fmadd4(o, q4.x, S0); fmadd4(o, q4.y, S1);
    fmadd4(o, q4.z, S2); fmadd4(o, q4.w, S3);
    o.x *= e4.x; o.y *= e4.y; o.z *= e4.z; o.w *= e4.w;
    *reinterpret_cast<float4*>(op + (size_t)t * C) = o;
  }
}

extern "C" void kernel_launch(void* const* d_in, const int* in_sizes, int n_in,
                              void* d_out, int out_size, void* d_ws, size_t ws_size,
                              hipStream_t stream) {
  const float* xq  = (const float*)d_in[0];
  const float* xk  = (const float*)d_in[1];
  const float* xv  = (const float*)d_in[2];
  const float* emb = (const float*)d_in[3];
  float*  out  = (float*)d_out;
  float4* part = (float4*)d_ws;   // 4 MiB

  k_partial<<<NBLK, 512, 0, stream>>>(xk, xv, part);
  k_scan<<<B * 32, 512, 0, stream>>>((float*)d_ws);
  k_out<<<NBLK, 512, 0, stream>>>(xq, xk, xv, emb, part, out);
}